// Round 1
// baseline (221.818 us; speedup 1.0000x reference)
//
#include <hip/hip_runtime.h>

#define NH  16
#define SQL 1024
#define SKV 4096
#define HD  128
#define TK  64

__global__ __launch_bounds__(256) void dsa_sparse_attn(
    const float* __restrict__ q, const float* __restrict__ k,
    const float* __restrict__ v, const int* __restrict__ tidx,
    const float* __restrict__ tsc, float* __restrict__ out)
{
    // one wave per (h, s) pair; 4 waves per block
    __shared__ float4 qs4[4][HD / 4];   // staged q row per wave
    __shared__ int    idxs[4][TK];
    __shared__ float  wgts[4][TK];

    const int tid  = threadIdx.x;
    const int wv   = tid >> 6;
    const int lane = tid & 63;
    const int bi   = blockIdx.x;

    // XCD-locality swizzle: head h = 2*(bi%8) + (bi/8)%2 -> heads {2x,2x+1} stay on XCD x
    const int h = ((bi & 7) << 1) | ((bi >> 3) & 1);
    const int s = ((bi >> 4) << 2) + wv;

    // stage q[h,s,:] into LDS (float2 per lane, 64 lanes * 8B = 512B)
    const float* qp = q + (size_t)(h * SQL + s) * HD;
    float2 q2 = *(const float2*)(qp + lane * 2);
    ((float2*)&qs4[wv][0])[lane] = q2;

    // lane t owns topk entry t
    const int   t_idx = tidx[s * TK + lane];
    const float t_sc  = tsc[s * TK + lane];

    __syncthreads();

    // QK^T: lane t computes dot(q, K[idx_t]); scattered float4 global loads (cache-resident)
    const float* kp = k + (size_t)(h * SKV + t_idx) * HD;
    float acc = 0.f;
#pragma unroll
    for (int j = 0; j < HD / 4; ++j) {
        float4 k4 = *(const float4*)(kp + j * 4);
        float4 qq = qs4[wv][j];          // broadcast read, conflict-free
        acc += k4.x * qq.x + k4.y * qq.y + k4.z * qq.z + k4.w * qq.w;
    }
    acc *= 0.08838834764831845f;         // 1/sqrt(128)

    // fused softmax * topk_scores with renormalization:
    // w_t = e_t * ts_t / (sum(e*ts) + 1e-12 * sum(e))
    float m = acc;
#pragma unroll
    for (int off = 32; off; off >>= 1) m = fmaxf(m, __shfl_xor(m, off));
    float e    = __expf(acc - m);
    float ets  = e * t_sc;
    float se   = e, sets = ets;
#pragma unroll
    for (int off = 32; off; off >>= 1) {
        se   += __shfl_xor(se, off);
        sets += __shfl_xor(sets, off);
    }
    const float wgt = ets / (sets + 1e-12f * se);

    idxs[wv][lane] = t_idx;
    wgts[wv][lane] = wgt;
    __syncthreads();

    // PV: iterate topk entries; idx/weight broadcast from LDS,
    // lanes load V row cooperatively (float2 -> 512B coalesced per instr)
    const float* vb = v + (size_t)h * SKV * HD;
    float o0 = 0.f, o1 = 0.f;
#pragma unroll 8
    for (int t = 0; t < TK; ++t) {
        const float* vp = vb + (size_t)idxs[wv][t] * HD;
        const float  wt = wgts[wv][t];
        float2 v2 = *(const float2*)(vp + lane * 2);
        o0 += wt * v2.x;
        o1 += wt * v2.y;
    }

    float* op = out + (size_t)(h * SQL + s) * HD;
    *(float2*)(op + lane * 2) = make_float2(o0, o1);
}

extern "C" void kernel_launch(void* const* d_in, const int* in_sizes, int n_in,
                              void* d_out, int out_size, void* d_ws, size_t ws_size,
                              hipStream_t stream) {
    const float* q  = (const float*)d_in[0];
    const float* k  = (const float*)d_in[1];
    const float* v  = (const float*)d_in[2];
    const int*   ti = (const int*)d_in[3];
    const float* ts = (const float*)d_in[4];
    float* out = (float*)d_out;

    // 16*1024 (h,s) pairs, 4 waves/block -> 4096 blocks
    dsa_sparse_attn<<<dim3(4096), dim3(256), 0, stream>>>(q, k, v, ti, ts, out);
}

// Round 2
// 165.316 us; speedup vs baseline: 1.3418x; 1.3418x over previous
//
#include <hip/hip_runtime.h>

#define NH  16
#define SQL 1024
#define SKV 4096
#define HD  128
#define TK  64

__global__ __launch_bounds__(256) void dsa_sparse_attn(
    const float* __restrict__ q, const float* __restrict__ k,
    const float* __restrict__ v, const int* __restrict__ tidx,
    const float* __restrict__ tsc, float* __restrict__ out)
{
    // one wave per (h, s); 4 waves per block; all LDS rows are wave-private
    __shared__ int   idxs[4][TK];
    __shared__ float wsc[4][TK];   // scores, then weights

    const int tid  = threadIdx.x;
    const int wv   = tid >> 6;
    const int lane = tid & 63;
    const int half = lane >> 5;    // which gathered row this half-wave loads
    const int l32  = lane & 31;    // covers dims 4*l32 .. 4*l32+3
    const int bi   = blockIdx.x;

    // XCD-locality swizzle: heads {2x,2x+1} stay on XCD x
    const int h = ((bi & 7) << 1) | ((bi >> 3) & 1);
    const int s = ((bi >> 4) << 2) + wv;

    // q fragment in registers (same fragment in both halves; broadcast load)
    const float* qp = q + (size_t)(h * SQL + s) * HD;
    const float4 qf = *(const float4*)(qp + 4 * l32);

    // topk entries (coalesced); own entry kept in reg for softmax phase
    const int   t_idx = tidx[s * TK + lane];
    const float t_sc  = tsc[s * TK + lane];
    idxs[wv][lane] = t_idx;
    (void)t_idx;

    // ---- QK^T: 2 gathered K rows per iteration, fully-coalesced float4 loads
    const float* kb = k + (size_t)h * SKV * HD;
#pragma unroll 4
    for (int i = 0; i < TK / 2; ++i) {
        const int t   = 2 * i + half;
        const int row = idxs[wv][t];           // 2-addr LDS broadcast (free)
        float4 k4 = *(const float4*)(kb + (size_t)row * HD + 4 * l32);
        float d = k4.x * qf.x + k4.y * qf.y + k4.z * qf.z + k4.w * qf.w;
        // reduce over the 32-lane half that holds this row
        d += __shfl_xor(d, 16);
        d += __shfl_xor(d, 8);
        d += __shfl_xor(d, 4);
        d += __shfl_xor(d, 2);
        d += __shfl_xor(d, 1);
        if (l32 == 0) wsc[wv][t] = d;          // lanes 0 and 32 write t=2i, 2i+1
    }

    // ---- fused softmax * topk_scores, renormalized:
    // w_t = e_t*ts_t / (sum(e*ts) + 1e-12*sum(e))
    float acc = wsc[wv][lane] * 0.08838834764831845f;  // 1/sqrt(128)
    float m = acc;
#pragma unroll
    for (int off = 32; off; off >>= 1) m = fmaxf(m, __shfl_xor(m, off));
    const float e   = __expf(acc - m);
    const float ets = e * t_sc;
    float se = e, sets = ets;
#pragma unroll
    for (int off = 32; off; off >>= 1) {
        se   += __shfl_xor(se, off);
        sets += __shfl_xor(sets, off);
    }
    wsc[wv][lane] = ets / (sets + 1e-12f * se);

    // ---- PV: 2 gathered V rows per iteration, coalesced float4 loads
    const float* vb = v + (size_t)h * SKV * HD;
    float4 o = make_float4(0.f, 0.f, 0.f, 0.f);
#pragma unroll 4
    for (int i = 0; i < TK / 2; ++i) {
        const int t    = 2 * i + half;
        const int row  = idxs[wv][t];
        const float wt = wsc[wv][t];
        float4 v4 = *(const float4*)(vb + (size_t)row * HD + 4 * l32);
        o.x += wt * v4.x;
        o.y += wt * v4.y;
        o.z += wt * v4.z;
        o.w += wt * v4.w;
    }
    // halves accumulated disjoint t subsets of the same dims -> combine
    o.x += __shfl_xor(o.x, 32);
    o.y += __shfl_xor(o.y, 32);
    o.z += __shfl_xor(o.z, 32);
    o.w += __shfl_xor(o.w, 32);

    if (half == 0) {
        *(float4*)(out + (size_t)(h * SQL + s) * HD + 4 * l32) = o;
    }
}

extern "C" void kernel_launch(void* const* d_in, const int* in_sizes, int n_in,
                              void* d_out, int out_size, void* d_ws, size_t ws_size,
                              hipStream_t stream) {
    const float* q  = (const float*)d_in[0];
    const float* k  = (const float*)d_in[1];
    const float* v  = (const float*)d_in[2];
    const int*   ti = (const int*)d_in[3];
    const float* ts = (const float*)d_in[4];
    float* out = (float*)d_out;

    // 16*1024 (h,s) pairs, 4 waves/block -> 4096 blocks
    dsa_sparse_attn<<<dim3(4096), dim3(256), 0, stream>>>(q, k, v, ti, ts, out);
}

// Round 3
// 161.400 us; speedup vs baseline: 1.3743x; 1.0243x over previous
//
#include <hip/hip_runtime.h>

#define NH  16
#define SQL 1024
#define SKV 4096
#define HD  128
#define TK  64

// Block ordering: blocks 0..2047 -> heads 0..7 (head = bi%8 = XCD), blocks
// 2048..4095 -> heads 8..15. With 8 blocks/CU the first half exactly fills the
// GPU, so each XCD's L2 sees ONE head's K (2 MB) at a time (4 MB L2).
__device__ __forceinline__ void map_hs(int bi, int wv, int& h, int& s) {
    h = ((bi >> 11) << 3) | (bi & 7);
    s = (((bi >> 3) & 255) << 2) + wv;
}

// ---- Kernel 1: QK^T + fused softmax*topk_scores -> weights stash ----
__global__ __launch_bounds__(256) void qk_softmax_k(
    const float* __restrict__ q, const float* __restrict__ k,
    const int* __restrict__ tidx, const float* __restrict__ tsc,
    float* __restrict__ wstash)   // [NH*SQL*TK]
{
    __shared__ int   idxs[4][TK];
    __shared__ float wsc[4][TK];

    const int tid  = threadIdx.x;
    const int wv   = tid >> 6;
    const int lane = tid & 63;
    const int half = lane >> 5;
    const int l32  = lane & 31;
    int h, s;
    map_hs(blockIdx.x, wv, h, s);

    const float* qp = q + (size_t)(h * SQL + s) * HD;
    const float4 qf = *(const float4*)(qp + 4 * l32);

    const float t_sc = tsc[s * TK + lane];
    idxs[wv][lane] = tidx[s * TK + lane];

    const float* kb = k + (size_t)h * SKV * HD;
#pragma unroll 4
    for (int i = 0; i < TK / 2; ++i) {
        const int t   = 2 * i + half;
        const int row = idxs[wv][t];
        float4 k4 = *(const float4*)(kb + (size_t)row * HD + 4 * l32);
        float d = k4.x * qf.x + k4.y * qf.y + k4.z * qf.z + k4.w * qf.w;
        d += __shfl_xor(d, 16);
        d += __shfl_xor(d, 8);
        d += __shfl_xor(d, 4);
        d += __shfl_xor(d, 2);
        d += __shfl_xor(d, 1);
        if (l32 == 0) wsc[wv][t] = d;
    }

    // w_t = e_t*ts_t / (sum(e*ts) + 1e-12*sum(e))
    float acc = wsc[wv][lane] * 0.08838834764831845f;
    float m = acc;
#pragma unroll
    for (int off = 32; off; off >>= 1) m = fmaxf(m, __shfl_xor(m, off));
    const float e   = __expf(acc - m);
    const float ets = e * t_sc;
    float se = e, sets = ets;
#pragma unroll
    for (int off = 32; off; off >>= 1) {
        se   += __shfl_xor(se, off);
        sets += __shfl_xor(sets, off);
    }
    wstash[(size_t)(h * SQL + s) * TK + lane] = ets / (sets + 1e-12f * se);
}

// ---- Kernel 2: PV gather-accumulate ----
template <int STASH_IN_OUT>
__global__ __launch_bounds__(256) void pv_k(
    const float* __restrict__ v, const int* __restrict__ tidx,
    const float* __restrict__ wstash, float* __restrict__ out)
{
    __shared__ int   idxs[4][TK];
    __shared__ float wgts[4][TK];

    const int tid  = threadIdx.x;
    const int wv   = tid >> 6;
    const int lane = tid & 63;
    const int half = lane >> 5;
    const int l32  = lane & 31;
    int h, s;
    map_hs(blockIdx.x, wv, h, s);

    const size_t hs = (size_t)(h * SQL + s);
    idxs[wv][lane] = tidx[s * TK + lane];
    wgts[wv][lane] = STASH_IN_OUT ? wstash[hs * HD + lane]
                                  : wstash[hs * TK + lane];

    const float* vb = v + (size_t)h * SKV * HD;
    float4 o = make_float4(0.f, 0.f, 0.f, 0.f);
#pragma unroll 4
    for (int i = 0; i < TK / 2; ++i) {
        const int t    = 2 * i + half;
        const int row  = idxs[wv][t];
        const float wt = wgts[wv][t];
        float4 v4 = *(const float4*)(vb + (size_t)row * HD + 4 * l32);
        o.x += wt * v4.x;
        o.y += wt * v4.y;
        o.z += wt * v4.z;
        o.w += wt * v4.w;
    }
    o.x += __shfl_xor(o.x, 32);
    o.y += __shfl_xor(o.y, 32);
    o.z += __shfl_xor(o.z, 32);
    o.w += __shfl_xor(o.w, 32);

    if (half == 0) {
        *(float4*)(out + hs * HD + 4 * l32) = o;
    }
}

extern "C" void kernel_launch(void* const* d_in, const int* in_sizes, int n_in,
                              void* d_out, int out_size, void* d_ws, size_t ws_size,
                              hipStream_t stream) {
    const float* q  = (const float*)d_in[0];
    const float* k  = (const float*)d_in[1];
    const float* v  = (const float*)d_in[2];
    const int*   ti = (const int*)d_in[3];
    const float* ts = (const float*)d_in[4];
    float* out = (float*)d_out;

    const size_t need = (size_t)NH * SQL * TK * sizeof(float);  // 4 MB
    if (ws_size >= need) {
        float* ws = (float*)d_ws;
        qk_softmax_k<<<dim3(4096), dim3(256), 0, stream>>>(q, k, ti, ts, ws);
        pv_k<0><<<dim3(4096), dim3(256), 0, stream>>>(v, ti, ws, out);
    } else {
        // stash weights in the first 64 floats of each output row; kernel 2
        // reads its own row's stash before overwriting the row (wave-ordered)
        qk_softmax_k<<<dim3(4096), dim3(256), 0, stream>>>(q, k, ti, ts, out);
        // repurpose stride: stash at out[hs*HD + lane]
        pv_k<1><<<dim3(4096), dim3(256), 0, stream>>>(v, ti, out, out);
    }
}

// Round 4
// 144.405 us; speedup vs baseline: 1.5361x; 1.1177x over previous
//
#include <hip/hip_runtime.h>

#define NH  16
#define SQL 1024
#define SKV 4096
#define HD  128
#define TK  64

__device__ __forceinline__ float blo(unsigned u) { return __uint_as_float(u << 16); }
__device__ __forceinline__ float bhi(unsigned u) { return __uint_as_float(u & 0xFFFF0000u); }

// ---- fp32 -> bf16 (RNE) streaming convert: 8 floats/thread ----
__global__ __launch_bounds__(256) void cvt_bf16(const float* __restrict__ src,
                                                unsigned short* __restrict__ dst,
                                                int n8) {
    int i = blockIdx.x * 256 + threadIdx.x;
    if (i >= n8) return;
    const float4* s4 = (const float4*)src;
    float4 a = s4[2 * i], b = s4[2 * i + 1];
    float f[8] = {a.x, a.y, a.z, a.w, b.x, b.y, b.z, b.w};
    unsigned r[8];
#pragma unroll
    for (int j = 0; j < 8; ++j) {
        unsigned u = __float_as_uint(f[j]);
        r[j] = (u + 0x7FFFu + ((u >> 16) & 1u)) >> 16;   // RNE
    }
    uint4 o;
    o.x = r[0] | (r[1] << 16);
    o.y = r[2] | (r[3] << 16);
    o.z = r[4] | (r[5] << 16);
    o.w = r[6] | (r[7] << 16);
    ((uint4*)dst)[i] = o;
}

// ---- combined QK->softmax->PV, bf16 gathered rows, 4 rows/instr ----
__global__ __launch_bounds__(256) void dsa_bf16(
    const float* __restrict__ q, const unsigned short* __restrict__ kb16,
    const unsigned short* __restrict__ vb16, const int* __restrict__ tidx,
    const float* __restrict__ tsc, float* __restrict__ out)
{
    __shared__ int   idxs[4][TK];
    __shared__ float wsc[4][TK];

    const int tid  = threadIdx.x;
    const int wv   = tid >> 6;
    const int lane = tid & 63;
    const int quad = lane >> 4;    // which of 4 gathered rows this 16-lane group loads
    const int l16  = lane & 15;    // covers dims 8*l16 .. 8*l16+7
    const int bi   = blockIdx.x;

    // one head per XCD at a time: blocks 0..2047 -> heads 0..7 (= bi%8 = XCD)
    const int h = ((bi >> 11) << 3) | (bi & 7);
    const int s = (((bi >> 3) & 255) << 2) + wv;

    // q fragment: 8 fp32 dims per lane (replicated across the 4 quads)
    const float* qp = q + (size_t)(h * SQL + s) * HD + 8 * l16;
    const float4 qa = *(const float4*)qp;
    const float4 qb = *(const float4*)(qp + 4);

    idxs[wv][lane] = tidx[s * TK + lane];
    const float t_sc = tsc[s * TK + lane];

    // ---- QK^T: 4 bf16 rows per instruction (64 lanes x 16B = 4 x 256B rows)
    const unsigned short* kb = kb16 + (size_t)h * SKV * HD;
#pragma unroll 8
    for (int i = 0; i < TK / 4; ++i) {
        const int t   = 4 * i + quad;
        const int row = idxs[wv][t];          // wave-private LDS, broadcast x16
        uint4 kw = *(const uint4*)(kb + (size_t)row * HD + 8 * l16);
        float d;
        d  = qa.x * blo(kw.x) + qa.y * bhi(kw.x);
        d += qa.z * blo(kw.y) + qa.w * bhi(kw.y);
        d += qb.x * blo(kw.z) + qb.y * bhi(kw.z);
        d += qb.z * blo(kw.w) + qb.w * bhi(kw.w);
        d += __shfl_xor(d, 8);
        d += __shfl_xor(d, 4);
        d += __shfl_xor(d, 2);
        d += __shfl_xor(d, 1);
        if (l16 == 0) wsc[wv][t] = d;         // lanes 0,16,32,48
    }

    // ---- fused softmax * topk_scores, renormalized:
    // w_t = e_t*ts_t / (sum(e*ts) + 1e-12*sum(e))
    float acc = wsc[wv][lane] * 0.08838834764831845f;   // 1/sqrt(128)
    float m = acc;
#pragma unroll
    for (int off = 32; off; off >>= 1) m = fmaxf(m, __shfl_xor(m, off));
    const float e   = __expf(acc - m);
    const float ets = e * t_sc;
    float se = e, sets = ets;
#pragma unroll
    for (int off = 32; off; off >>= 1) {
        se   += __shfl_xor(se, off);
        sets += __shfl_xor(sets, off);
    }
    wsc[wv][lane] = ets / (sets + 1e-12f * se);

    // ---- PV: 4 bf16 rows per instruction
    const unsigned short* vb = vb16 + (size_t)h * SKV * HD;
    float o[8] = {0.f, 0.f, 0.f, 0.f, 0.f, 0.f, 0.f, 0.f};
#pragma unroll 8
    for (int i = 0; i < TK / 4; ++i) {
        const int t    = 4 * i + quad;
        const int row  = idxs[wv][t];
        const float wt = wsc[wv][t];
        uint4 vw = *(const uint4*)(vb + (size_t)row * HD + 8 * l16);
        o[0] += wt * blo(vw.x);  o[1] += wt * bhi(vw.x);
        o[2] += wt * blo(vw.y);  o[3] += wt * bhi(vw.y);
        o[4] += wt * blo(vw.z);  o[5] += wt * bhi(vw.z);
        o[6] += wt * blo(vw.w);  o[7] += wt * bhi(vw.w);
    }
    // quads hold disjoint t-subsets of the same dims -> combine
#pragma unroll
    for (int j = 0; j < 8; ++j) {
        o[j] += __shfl_xor(o[j], 16);
        o[j] += __shfl_xor(o[j], 32);
    }
    if (quad == 0) {
        float* op = out + (size_t)(h * SQL + s) * HD + 8 * l16;
        *(float4*)op       = make_float4(o[0], o[1], o[2], o[3]);
        *(float4*)(op + 4) = make_float4(o[4], o[5], o[6], o[7]);
    }
}

// ---- fp32 fallback (round-1 kernel) if workspace too small ----
__global__ __launch_bounds__(256) void dsa_fp32(
    const float* __restrict__ q, const float* __restrict__ k,
    const float* __restrict__ v, const int* __restrict__ tidx,
    const float* __restrict__ tsc, float* __restrict__ out)
{
    __shared__ int   idxs[4][TK];
    __shared__ float wsc[4][TK];
    const int tid = threadIdx.x, wv = tid >> 6, lane = tid & 63;
    const int half = lane >> 5, l32 = lane & 31, bi = blockIdx.x;
    const int h = ((bi & 7) << 1) | ((bi >> 3) & 1);
    const int s = ((bi >> 4) << 2) + wv;
    const float* qp = q + (size_t)(h * SQL + s) * HD;
    const float4 qf = *(const float4*)(qp + 4 * l32);
    const float t_sc = tsc[s * TK + lane];
    idxs[wv][lane] = tidx[s * TK + lane];
    const float* kb = k + (size_t)h * SKV * HD;
#pragma unroll 4
    for (int i = 0; i < TK / 2; ++i) {
        const int t = 2 * i + half, row = idxs[wv][t];
        float4 k4 = *(const float4*)(kb + (size_t)row * HD + 4 * l32);
        float d = k4.x * qf.x + k4.y * qf.y + k4.z * qf.z + k4.w * qf.w;
        d += __shfl_xor(d, 16); d += __shfl_xor(d, 8); d += __shfl_xor(d, 4);
        d += __shfl_xor(d, 2);  d += __shfl_xor(d, 1);
        if (l32 == 0) wsc[wv][t] = d;
    }
    float acc = wsc[wv][lane] * 0.08838834764831845f;
    float m = acc;
#pragma unroll
    for (int off = 32; off; off >>= 1) m = fmaxf(m, __shfl_xor(m, off));
    const float e = __expf(acc - m), ets = e * t_sc;
    float se = e, sets = ets;
#pragma unroll
    for (int off = 32; off; off >>= 1) { se += __shfl_xor(se, off); sets += __shfl_xor(sets, off); }
    wsc[wv][lane] = ets / (sets + 1e-12f * se);
    const float* vbp = v + (size_t)h * SKV * HD;
    float4 o = make_float4(0.f, 0.f, 0.f, 0.f);
#pragma unroll 4
    for (int i = 0; i < TK / 2; ++i) {
        const int t = 2 * i + half, row = idxs[wv][t];
        const float wt = wsc[wv][t];
        float4 v4 = *(const float4*)(vbp + (size_t)row * HD + 4 * l32);
        o.x += wt * v4.x; o.y += wt * v4.y; o.z += wt * v4.z; o.w += wt * v4.w;
    }
    o.x += __shfl_xor(o.x, 32); o.y += __shfl_xor(o.y, 32);
    o.z += __shfl_xor(o.z, 32); o.w += __shfl_xor(o.w, 32);
    if (half == 0) *(float4*)(out + (size_t)(h * SQL + s) * HD + 4 * l32) = o;
}

extern "C" void kernel_launch(void* const* d_in, const int* in_sizes, int n_in,
                              void* d_out, int out_size, void* d_ws, size_t ws_size,
                              hipStream_t stream) {
    const float* q  = (const float*)d_in[0];
    const float* k  = (const float*)d_in[1];
    const float* v  = (const float*)d_in[2];
    const int*   ti = (const int*)d_in[3];
    const float* ts = (const float*)d_in[4];
    float* out = (float*)d_out;

    const size_t nkv  = (size_t)NH * SKV * HD;            // 8.4M elems each
    const size_t need = 2 * nkv * sizeof(unsigned short); // 33.6 MB
    if (ws_size >= need) {
        unsigned short* kb16 = (unsigned short*)d_ws;
        unsigned short* vb16 = kb16 + nkv;
        const int n8 = (int)(nkv / 8);                    // 1,048,576
        cvt_bf16<<<dim3(n8 / 256), dim3(256), 0, stream>>>(k, kb16, n8);
        cvt_bf16<<<dim3(n8 / 256), dim3(256), 0, stream>>>(v, vb16, n8);
        dsa_bf16<<<dim3(4096), dim3(256), 0, stream>>>(q, kb16, vb16, ti, ts, out);
    } else {
        dsa_fp32<<<dim3(4096), dim3(256), 0, stream>>>(q, k, v, ti, ts, out);
    }
}